// Round 1
// baseline (188.266 us; speedup 1.0000x reference)
//
#include <hip/hip_runtime.h>

#define NEGV -1.0e12f
constexpr int B = 16, C = 384, Q = 64, D = 2048;
constexpr int CT = 8;    // rows per block in main kernel
constexpr int BK = 64;   // k-tile

// ---------------- kernel 1: per (b,i) q stats: q.w_q, q.W2col0, q.W2col1 ----
__global__ __launch_bounds__(256) void k_qstats(
    const float* __restrict__ q, const float* __restrict__ w_q,
    const float* __restrict__ W_out, float* __restrict__ qstats) {
  int bi = blockIdx.x;  // b*Q + i
  const float* qrow = q + (size_t)bi * D;
  int t = threadIdx.x;
  float a0 = 0.f, a1 = 0.f, a2 = 0.f;
  for (int d = t * 4; d < D; d += 256 * 4) {
    float4 qv = *(const float4*)(qrow + d);
    float4 wq = *(const float4*)(w_q + d);
    const float* wp = W_out + (size_t)(D + d) * 2;  // W2 rows
    float4 wa = *(const float4*)(wp);
    float4 wb = *(const float4*)(wp + 4);
    a0 += qv.x * wq.x + qv.y * wq.y + qv.z * wq.z + qv.w * wq.w;
    a1 += qv.x * wa.x + qv.y * wa.z + qv.z * wb.x + qv.w * wb.z;
    a2 += qv.x * wa.y + qv.y * wa.w + qv.z * wb.y + qv.w * wb.w;
  }
  for (int m = 1; m < 64; m <<= 1) {
    a0 += __shfl_xor(a0, m, 64);
    a1 += __shfl_xor(a1, m, 64);
    a2 += __shfl_xor(a2, m, 64);
  }
  __shared__ float red[3][4];
  int w = t >> 6, lane = t & 63;
  if (lane == 0) { red[0][w] = a0; red[1][w] = a1; red[2][w] = a2; }
  __syncthreads();
  if (t == 0) {
    qstats[bi * 3 + 0] = red[0][0] + red[0][1] + red[0][2] + red[0][3];
    qstats[bi * 3 + 1] = red[1][0] + red[1][1] + red[1][2] + red[1][3];
    qstats[bi * 3 + 2] = red[2][0] + red[2][1] + red[2][2] + red[2][3];
  }
}

// ---------------- kernel 2: main fused GEMM + row softmax --------------------
// grid (C/CT, B), block 256 (4 waves). Wave w owns rows {w, w+4}; lane = i.
__global__ __launch_bounds__(256) void k_main(
    const float* __restrict__ c, const float* __restrict__ q,
    const int* __restrict__ c_len, const int* __restrict__ q_len,
    const float* __restrict__ w_c, const float* __restrict__ b_c,
    const float* __restrict__ b_q, const float* __restrict__ w_cq,
    const float* __restrict__ b_cq, const float* __restrict__ W_out,
    const float* __restrict__ qstats, float* __restrict__ mrow,
    float* __restrict__ out12) {
  int t = threadIdx.x;
  int b = blockIdx.y;
  int r0 = blockIdx.x * CT;
  const float* crow_base = c + ((size_t)b * C + r0) * D;

  // pre-pass: per-row stats  c.w_c, c.W1col0, c.W1col1
  __shared__ float stats[CT][3];
  {
    int rr = t >> 5;      // 0..7 : row
    int j = t & 31;
    const float* crow = crow_base + (size_t)rr * D;
    float s0 = 0.f, s1 = 0.f, s2 = 0.f;
    for (int d = j * 4; d < D; d += 32 * 4) {
      float4 cv = *(const float4*)(crow + d);
      float4 wc = *(const float4*)(w_c + d);
      const float* wp = W_out + (size_t)d * 2;  // W1 rows
      float4 wa = *(const float4*)(wp);
      float4 wb = *(const float4*)(wp + 4);
      s0 += cv.x * wc.x + cv.y * wc.y + cv.z * wc.z + cv.w * wc.w;
      s1 += cv.x * wa.x + cv.y * wa.z + cv.z * wb.x + cv.w * wb.z;
      s2 += cv.x * wa.y + cv.y * wa.w + cv.z * wb.y + cv.w * wb.w;
    }
    for (int m = 1; m < 32; m <<= 1) {
      s0 += __shfl_xor(s0, m, 64);
      s1 += __shfl_xor(s1, m, 64);
      s2 += __shfl_xor(s2, m, 64);
    }
    if (j == 0) { stats[rr][0] = s0; stats[rr][1] = s1; stats[rr][2] = s2; }
  }

  __shared__ float c_sh[CT][BK + 4];
  __shared__ float q_sh[Q][BK + 4];
  int wv = t >> 6, lane = t & 63;
  float acc0[2] = {0.f, 0.f};  // c*q*w_cq
  float acc1[2] = {0.f, 0.f};  // c*q*W3col0
  float acc2[2] = {0.f, 0.f};  // c*q*W3col1
  const float* qbase = q + (size_t)b * Q * D;

  for (int k0 = 0; k0 < D; k0 += BK) {
    __syncthreads();
    if (t < 128) {  // stage c tile: 8*64 floats
      int rr = t >> 4, kq = (t & 15) * 4;
      *(float4*)&c_sh[rr][kq] =
          *(const float4*)(crow_base + (size_t)rr * D + k0 + kq);
    }
    for (int m = 0; m < 4; m++) {  // stage q tile: 64*64 floats
      int idx = t + 256 * m;
      int qr = idx >> 4, kq = (idx & 15) * 4;
      *(float4*)&q_sh[qr][kq] =
          *(const float4*)(qbase + (size_t)qr * D + k0 + kq);
    }
    __syncthreads();
    for (int k4 = 0; k4 < BK; k4 += 4) {
      float4 qv = *(const float4*)&q_sh[lane][k4];
      float4 wv4 = *(const float4*)(w_cq + k0 + k4);
      const float* wp = W_out + (size_t)(2 * D + k0 + k4) * 2;  // W3 rows
      float4 wa = *(const float4*)(wp);
      float4 wb = *(const float4*)(wp + 4);
#pragma unroll
      for (int rr = 0; rr < 2; rr++) {
        float4 cv = *(const float4*)&c_sh[wv + 4 * rr][k4];
        float px = cv.x * qv.x, py = cv.y * qv.y;
        float pz = cv.z * qv.z, pw = cv.w * qv.w;
        acc0[rr] += px * wv4.x + py * wv4.y + pz * wv4.z + pw * wv4.w;
        acc1[rr] += px * wa.x + py * wa.z + pz * wb.x + pw * wb.z;
        acc2[rr] += px * wa.y + py * wa.w + pz * wb.y + pw * wb.w;
      }
    }
  }

  int cl = c_len[b], ql = q_len[b];
  float bc = b_c[0], bq = b_q[0], bcq = b_cq[0];
  float qs0 = qstats[((b << 6) + lane) * 3 + 0];
  float qs1 = qstats[((b << 6) + lane) * 3 + 1];
  float qs2 = qstats[((b << 6) + lane) * 3 + 2];
#pragma unroll
  for (int rr = 0; rr < 2; rr++) {
    int rl = wv + 4 * rr;
    int rg = r0 + rl;
    float s = acc0[rr] + stats[rl][0] + qs0 + bc + bq + bcq;
    bool masked = (lane >= ql) || ((rg >= cl) && (lane < Q - 1));
    if (masked) s += NEGV;
    float mx = s;
    for (int m = 1; m < 64; m <<= 1) mx = fmaxf(mx, __shfl_xor(mx, m, 64));
    float e = __expf(s - mx);
    float den = e;
    for (int m = 1; m < 64; m <<= 1) den += __shfl_xor(den, m, 64);
    float a = e / den;
    float v0 = a * qs1;        // -> term2 col0
    float v1 = a * qs2;        // -> term2 col1
    float v2 = a * acc1[rr];   // -> term3 col0
    float v3 = a * acc2[rr];   // -> term3 col1
    for (int m = 1; m < 64; m <<= 1) {
      v0 += __shfl_xor(v0, m, 64);
      v1 += __shfl_xor(v1, m, 64);
      v2 += __shfl_xor(v2, m, 64);
      v3 += __shfl_xor(v3, m, 64);
    }
    if (lane == 0) {
      mrow[b * C + rg] = mx;
      out12[(b * C + rg) * 2 + 0] = stats[rl][1] + v0 + v2;
      out12[(b * C + rg) * 2 + 1] = stats[rl][2] + v1 + v3;
    }
  }
}

// ---------------- kernel 3: b_att softmax + q2c ------------------------------
// grid (16, B): 128-wide d-chunks. block 256.
__global__ __launch_bounds__(256) void k_q2c(const float* __restrict__ c,
                                             const float* __restrict__ mrow,
                                             float* __restrict__ q2c) {
  int b = blockIdx.y;
  int d0 = blockIdx.x * 128;
  int t = threadIdx.x;
  __shared__ float batt[C];
  __shared__ float red_mx[4];
  __shared__ float red_sm[4];
  __shared__ float part[128];

  float m1 = mrow[b * C + t];
  float m2 = (t < C - 256) ? mrow[b * C + 256 + t] : -3.0e38f;
  float mx = fmaxf(m1, m2);
  for (int m = 1; m < 64; m <<= 1) mx = fmaxf(mx, __shfl_xor(mx, m, 64));
  if ((t & 63) == 0) red_mx[t >> 6] = mx;
  __syncthreads();
  mx = fmaxf(fmaxf(red_mx[0], red_mx[1]), fmaxf(red_mx[2], red_mx[3]));
  float e1 = __expf(m1 - mx);
  float e2 = (t < C - 256) ? __expf(m2 - mx) : 0.f;
  float sum = e1 + e2;
  for (int m = 1; m < 64; m <<= 1) sum += __shfl_xor(sum, m, 64);
  if ((t & 63) == 0) red_sm[t >> 6] = sum;
  __syncthreads();
  sum = red_sm[0] + red_sm[1] + red_sm[2] + red_sm[3];
  batt[t] = e1 / sum;
  if (t < C - 256) batt[256 + t] = e2 / sum;
  __syncthreads();

  int dl = t & 127;
  int half = t >> 7;
  const float* cb = c + (size_t)b * C * D + d0 + dl;
  float acc = 0.f;
  for (int r = half * 192; r < half * 192 + 192; r++)
    acc += batt[r] * cb[(size_t)r * D];
  if (half == 1) part[dl] = acc;
  __syncthreads();
  if (half == 0) q2c[(size_t)b * D + d0 + dl] = acc + part[dl];
}

// ---------------- kernel 4: term4 + bias + final mask + write ---------------
__global__ __launch_bounds__(256) void k_out(
    const float* __restrict__ c, const float* __restrict__ q2c,
    const float* __restrict__ W_out, const float* __restrict__ b_out,
    const float* __restrict__ out12, const int* __restrict__ c_len,
    float* __restrict__ outp) {
  int idx = blockIdx.x;  // b*C + r
  int b = idx / C, r = idx % C;
  const float* crow = c + (size_t)idx * D;
  const float* v = q2c + (size_t)b * D;
  int t = threadIdx.x;
  float a0 = 0.f, a1 = 0.f;
  for (int d = t * 4; d < D; d += 1024) {
    float4 cv = *(const float4*)(crow + d);
    float4 vv = *(const float4*)(v + d);
    const float* wp = W_out + (size_t)(3 * D + d) * 2;  // W4 rows
    float4 wa = *(const float4*)(wp);
    float4 wb = *(const float4*)(wp + 4);
    float px = cv.x * vv.x, py = cv.y * vv.y;
    float pz = cv.z * vv.z, pw = cv.w * vv.w;
    a0 += px * wa.x + py * wa.z + pz * wb.x + pw * wb.z;
    a1 += px * wa.y + py * wa.w + pz * wb.y + pw * wb.w;
  }
  for (int m = 1; m < 64; m <<= 1) {
    a0 += __shfl_xor(a0, m, 64);
    a1 += __shfl_xor(a1, m, 64);
  }
  __shared__ float red[2][4];
  int w = t >> 6, lane = t & 63;
  if (lane == 0) { red[0][w] = a0; red[1][w] = a1; }
  __syncthreads();
  if (t == 0) {
    float o0 = out12[idx * 2 + 0] + red[0][0] + red[0][1] + red[0][2] +
               red[0][3] + b_out[0];
    float o1 = out12[idx * 2 + 1] + red[1][0] + red[1][1] + red[1][2] +
               red[1][3] + b_out[1];
    if (r >= c_len[b] && r < C - 1) { o0 = NEGV; o1 = NEGV; }
    outp[idx] = o0;
    outp[B * C + idx] = o1;
  }
}

extern "C" void kernel_launch(void* const* d_in, const int* in_sizes, int n_in,
                              void* d_out, int out_size, void* d_ws,
                              size_t ws_size, hipStream_t stream) {
  const float* c = (const float*)d_in[0];
  const float* q = (const float*)d_in[1];
  const int* c_len = (const int*)d_in[2];
  const int* q_len = (const int*)d_in[3];
  const float* w_c = (const float*)d_in[4];
  const float* b_c = (const float*)d_in[5];
  const float* w_q = (const float*)d_in[6];
  const float* b_q = (const float*)d_in[7];
  const float* w_cq = (const float*)d_in[8];
  const float* b_cq = (const float*)d_in[9];
  const float* W_out = (const float*)d_in[10];
  const float* b_out = (const float*)d_in[11];
  float* outp = (float*)d_out;

  float* ws = (float*)d_ws;
  float* qstats = ws;                         // B*Q*3  = 3072
  float* mrow = ws + 3072;                    // B*C    = 6144
  float* out12 = ws + 3072 + 6144;            // B*C*2  = 12288
  float* q2c = ws + 3072 + 6144 + 12288;      // B*D    = 32768

  hipLaunchKernelGGL(k_qstats, dim3(B * Q), dim3(256), 0, stream, q, w_q,
                     W_out, qstats);
  hipLaunchKernelGGL(k_main, dim3(C / CT, B), dim3(256), 0, stream, c, q,
                     c_len, q_len, w_c, b_c, b_q, w_cq, b_cq, W_out, qstats,
                     mrow, out12);
  hipLaunchKernelGGL(k_q2c, dim3(16, B), dim3(256), 0, stream, c, mrow, q2c);
  hipLaunchKernelGGL(k_out, dim3(B * C), dim3(256), 0, stream, c, q2c, W_out,
                     b_out, out12, c_len, outp);
}

// Round 2
// 138.866 us; speedup vs baseline: 1.3557x; 1.3557x over previous
//
#include <hip/hip_runtime.h>

#define NEGV -1.0e12f
constexpr int B = 16, C = 384, Q = 64, D = 2048;
constexpr int MB = 32;    // c-rows per block
constexpr int NB = 208;   // B-matrix rows: 3*64 streams + 3 stats + 13 zero-pad
constexpr int LP = 72;    // LDS pitch in bf16 (64 data + 8 pad -> 144B rows)
constexpr int NSTEP = D / 64;

typedef __attribute__((ext_vector_type(8))) short s16x8;
typedef __attribute__((ext_vector_type(4))) float f32x4;

__device__ __forceinline__ unsigned pkbf(float lo, float hi) {
  unsigned ulo = __builtin_bit_cast(unsigned, lo);
  unsigned uhi = __builtin_bit_cast(unsigned, hi);
  return (uhi & 0xFFFF0000u) | (ulo >> 16);
}

// ---------------- kernel 1: per (b,i) q stats: q.w_q, q.W2col0, q.W2col1 ----
__global__ __launch_bounds__(256) void k_qstats(
    const float* __restrict__ q, const float* __restrict__ w_q,
    const float* __restrict__ W_out, float* __restrict__ qstats) {
  int bi = blockIdx.x;
  const float* qrow = q + (size_t)bi * D;
  int t = threadIdx.x;
  float a0 = 0.f, a1 = 0.f, a2 = 0.f;
  for (int d = t * 4; d < D; d += 256 * 4) {
    float4 qv = *(const float4*)(qrow + d);
    float4 wq = *(const float4*)(w_q + d);
    const float* wp = W_out + (size_t)(D + d) * 2;
    float4 wa = *(const float4*)(wp);
    float4 wb = *(const float4*)(wp + 4);
    a0 += qv.x * wq.x + qv.y * wq.y + qv.z * wq.z + qv.w * wq.w;
    a1 += qv.x * wa.x + qv.y * wa.z + qv.z * wb.x + qv.w * wb.z;
    a2 += qv.x * wa.y + qv.y * wa.w + qv.z * wb.y + qv.w * wb.w;
  }
  for (int m = 1; m < 64; m <<= 1) {
    a0 += __shfl_xor(a0, m, 64);
    a1 += __shfl_xor(a1, m, 64);
    a2 += __shfl_xor(a2, m, 64);
  }
  __shared__ float red[3][4];
  int w = t >> 6, lane = t & 63;
  if (lane == 0) { red[0][w] = a0; red[1][w] = a1; red[2][w] = a2; }
  __syncthreads();
  if (t == 0) {
    qstats[bi * 3 + 0] = red[0][0] + red[0][1] + red[0][2] + red[0][3];
    qstats[bi * 3 + 1] = red[1][0] + red[1][1] + red[1][2] + red[1][3];
    qstats[bi * 3 + 2] = red[2][0] + red[2][1] + red[2][2] + red[2][3];
  }
}

// ---------------- kernel 2: MFMA GEMM + fused stats + row softmax -----------
// grid (C/MB, B), 256 threads (4 waves). Wave wv owns N-frag group; all waves
// cover all 32 rows. N layout: [0,64): q*w_cq, [64,128): q*W3c0, [128,192):
// q*W3c1, 192..194: {w_c, W1c0, W1c1} (row stats via GEMM), 195..207: zero.
__global__ __launch_bounds__(256, 1) void k_gemm(
    const float* __restrict__ c, const float* __restrict__ q,
    const int* __restrict__ c_len, const int* __restrict__ q_len,
    const float* __restrict__ w_c, const float* __restrict__ b_c,
    const float* __restrict__ b_q, const float* __restrict__ w_cq,
    const float* __restrict__ b_cq, const float* __restrict__ W_out,
    const float* __restrict__ qstats, float* __restrict__ mrow,
    float* __restrict__ out12) {
  const int t = threadIdx.x;
  const int b = blockIdx.y;
  const int r0 = blockIdx.x * MB;
  const int lane = t & 63;
  const int wv = t >> 6;

  __shared__ union SM {
    unsigned short st[(MB + NB) * LP];  // A tile then B tile, bf16 bits
    float S3[MB][212];                  // epilogue scores (union reuse)
  } sm;

  // zero the pad rows 195..207 once (never re-written in the K loop)
  if (t < 104) {
    int row = 195 + (t >> 3);
    int kk = (t & 7) * 8;
    *reinterpret_cast<uint4*>(&sm.st[(MB + row) * LP + kk]) =
        make_uint4(0u, 0u, 0u, 0u);
  }

  const int rowA = t >> 3, ksA = (t & 7) * 8;  // A staging role
  const int iB = t >> 2, ksB = (t & 3) * 16;   // B staging role
  const float* pA = c + ((size_t)b * C + r0 + rowA) * D + ksA;
  const float* pQ = q + ((size_t)b * Q + iB) * D + ksB;
  const float* pWq = w_cq + ksB;
  const float* pW3 = W_out + (size_t)4 * D + 2 * ksB;  // W3 region, stride-2
  const float* pWc = w_c + (t & 15) * 4;               // stats src (t<16)
  const float* pW1 = W_out + (t & 15) * 8;             // stats src (16<=t<32)

  float4 rA0, rA1, rQ[4], rWq[4], rW3[8], rS0, rS1;

  auto issue_loads = [&]() {
    rA0 = *(const float4*)(pA);
    rA1 = *(const float4*)(pA + 4);
#pragma unroll
    for (int j = 0; j < 4; ++j) rQ[j] = *(const float4*)(pQ + 4 * j);
#pragma unroll
    for (int j = 0; j < 4; ++j) rWq[j] = *(const float4*)(pWq + 4 * j);
#pragma unroll
    for (int j = 0; j < 8; ++j) rW3[j] = *(const float4*)(pW3 + 4 * j);
    if (t < 16) {
      rS0 = *(const float4*)(pWc);
    } else if (t < 32) {
      rS0 = *(const float4*)(pW1);
      rS1 = *(const float4*)(pW1 + 4);
    }
    pA += 64; pQ += 64; pWq += 64; pW3 += 128; pWc += 64; pW1 += 128;
  };

  auto write_lds = [&]() {
    uint4 wa;
    wa.x = pkbf(rA0.x, rA0.y); wa.y = pkbf(rA0.z, rA0.w);
    wa.z = pkbf(rA1.x, rA1.y); wa.w = pkbf(rA1.z, rA1.w);
    *reinterpret_cast<uint4*>(&sm.st[rowA * LP + ksA]) = wa;

    float qv[16], wq[16], w3[32];
#pragma unroll
    for (int j = 0; j < 4; ++j) {
      *(float4*)&qv[4 * j] = rQ[j];
      *(float4*)&wq[4 * j] = rWq[j];
    }
#pragma unroll
    for (int j = 0; j < 8; ++j) *(float4*)&w3[4 * j] = rW3[j];
    unsigned u0[8], u1[8], u2[8];
#pragma unroll
    for (int j = 0; j < 8; ++j) {
      float x0 = qv[2 * j], x1 = qv[2 * j + 1];
      u0[j] = pkbf(x0 * wq[2 * j], x1 * wq[2 * j + 1]);
      u1[j] = pkbf(x0 * w3[4 * j], x1 * w3[4 * j + 2]);
      u2[j] = pkbf(x0 * w3[4 * j + 1], x1 * w3[4 * j + 3]);
    }
    uint4 v;
    v.x = u0[0]; v.y = u0[1]; v.z = u0[2]; v.w = u0[3];
    *reinterpret_cast<uint4*>(&sm.st[(MB + iB) * LP + ksB]) = v;
    v.x = u0[4]; v.y = u0[5]; v.z = u0[6]; v.w = u0[7];
    *reinterpret_cast<uint4*>(&sm.st[(MB + iB) * LP + ksB + 8]) = v;
    v.x = u1[0]; v.y = u1[1]; v.z = u1[2]; v.w = u1[3];
    *reinterpret_cast<uint4*>(&sm.st[(MB + 64 + iB) * LP + ksB]) = v;
    v.x = u1[4]; v.y = u1[5]; v.z = u1[6]; v.w = u1[7];
    *reinterpret_cast<uint4*>(&sm.st[(MB + 64 + iB) * LP + ksB + 8]) = v;
    v.x = u2[0]; v.y = u2[1]; v.z = u2[2]; v.w = u2[3];
    *reinterpret_cast<uint4*>(&sm.st[(MB + 128 + iB) * LP + ksB]) = v;
    v.x = u2[4]; v.y = u2[5]; v.z = u2[6]; v.w = u2[7];
    *reinterpret_cast<uint4*>(&sm.st[(MB + 128 + iB) * LP + ksB + 8]) = v;

    if (t < 16) {
      uint2 s;
      s.x = pkbf(rS0.x, rS0.y); s.y = pkbf(rS0.z, rS0.w);
      *reinterpret_cast<uint2*>(&sm.st[(MB + 192) * LP + (t & 15) * 4]) = s;
    } else if (t < 32) {
      uint2 s;
      s.x = pkbf(rS0.x, rS0.z); s.y = pkbf(rS1.x, rS1.z);
      *reinterpret_cast<uint2*>(&sm.st[(MB + 193) * LP + (t & 15) * 4]) = s;
      s.x = pkbf(rS0.y, rS0.w); s.y = pkbf(rS1.y, rS1.w);
      *reinterpret_cast<uint2*>(&sm.st[(MB + 194) * LP + (t & 15) * 4]) = s;
    }
  };

  // N-frag assignment: wave0 -> frags 0..3, wave1 -> 4..6, wave2 -> 7..9,
  // wave3 -> 10..12 (13 frags = 208 cols)
  const int f0 = (wv == 0) ? 0 : (1 + 3 * wv);
  const int nf = (wv == 0) ? 4 : 3;
  const int lr = lane & 15;
  const int lk = (lane >> 4) * 8;

  f32x4 acc[2][4];
#pragma unroll
  for (int am = 0; am < 2; ++am)
#pragma unroll
    for (int f = 0; f < 4; ++f) acc[am][f] = f32x4{0.f, 0.f, 0.f, 0.f};

  auto compute = [&]() {
#pragma unroll
    for (int half = 0; half < 2; ++half) {
      const int kk = half * 32 + lk;
      s16x8 af[2];
#pragma unroll
      for (int am = 0; am < 2; ++am)
        af[am] =
            *reinterpret_cast<const s16x8*>(&sm.st[(am * 16 + lr) * LP + kk]);
      s16x8 bfr[4];
#pragma unroll
      for (int f = 0; f < 4; ++f)
        if (f < nf)
          bfr[f] = *reinterpret_cast<const s16x8*>(
              &sm.st[(MB + (f0 + f) * 16 + lr) * LP + kk]);
#pragma unroll
      for (int am = 0; am < 2; ++am)
#pragma unroll
        for (int f = 0; f < 4; ++f)
          if (f < nf)
            acc[am][f] = __builtin_amdgcn_mfma_f32_16x16x32_bf16(
                af[am], bfr[f], acc[am][f], 0, 0, 0);
    }
  };

  issue_loads();
  for (int s = 0; s < NSTEP; ++s) {
    __syncthreads();  // previous compute done reading LDS
    write_lds();
    if (s + 1 < NSTEP) issue_loads();  // in flight across compute
    __syncthreads();
    compute();
  }

  // ---- epilogue: frags -> S3, then per-row softmax/reduce ----
  __syncthreads();
#pragma unroll
  for (int am = 0; am < 2; ++am)
#pragma unroll
    for (int f = 0; f < 4; ++f)
      if (f < nf) {
        int colb = (f0 + f) * 16 + lr;
        int rb = am * 16 + (lane >> 4) * 4;
#pragma unroll
        for (int r2 = 0; r2 < 4; ++r2) sm.S3[rb + r2][colb] = acc[am][f][r2];
      }
  __syncthreads();

  const int cl = c_len[b], ql = q_len[b];
  const float bias = b_c[0] + b_q[0] + b_cq[0];
  const float qs0 = qstats[((b << 6) + lane) * 3 + 0];
  const float qs1 = qstats[((b << 6) + lane) * 3 + 1];
  const float qs2 = qstats[((b << 6) + lane) * 3 + 2];
#pragma unroll
  for (int rr = 0; rr < 8; ++rr) {
    int row = wv * 8 + rr;
    int rg = r0 + row;
    float s = sm.S3[row][lane] + sm.S3[row][192] + qs0 + bias;
    bool masked = (lane >= ql) || ((rg >= cl) && (lane < Q - 1));
    if (masked) s += NEGV;
    float mx = s;
    for (int m = 1; m < 64; m <<= 1) mx = fmaxf(mx, __shfl_xor(mx, m, 64));
    float e = __expf(s - mx);
    float den = e;
    for (int m = 1; m < 64; m <<= 1) den += __shfl_xor(den, m, 64);
    float a = e / den;
    float v0 = a * qs1;
    float v1 = a * qs2;
    float v2 = a * sm.S3[row][64 + lane];
    float v3 = a * sm.S3[row][128 + lane];
    for (int m = 1; m < 64; m <<= 1) {
      v0 += __shfl_xor(v0, m, 64);
      v1 += __shfl_xor(v1, m, 64);
      v2 += __shfl_xor(v2, m, 64);
      v3 += __shfl_xor(v3, m, 64);
    }
    if (lane == 0) {
      mrow[b * C + rg] = mx;
      out12[(b * C + rg) * 2 + 0] = sm.S3[row][193] + v0 + v2;
      out12[(b * C + rg) * 2 + 1] = sm.S3[row][194] + v1 + v3;
    }
  }
}

// ---------------- kernel 3: b_att softmax + q2c ------------------------------
__global__ __launch_bounds__(256) void k_q2c(const float* __restrict__ c,
                                             const float* __restrict__ mrow,
                                             float* __restrict__ q2c) {
  int b = blockIdx.y;
  int d0 = blockIdx.x * 128;
  int t = threadIdx.x;
  __shared__ float batt[C];
  __shared__ float red_mx[4];
  __shared__ float red_sm[4];
  __shared__ float part[128];

  float m1 = mrow[b * C + t];
  float m2 = (t < C - 256) ? mrow[b * C + 256 + t] : -3.0e38f;
  float mx = fmaxf(m1, m2);
  for (int m = 1; m < 64; m <<= 1) mx = fmaxf(mx, __shfl_xor(mx, m, 64));
  if ((t & 63) == 0) red_mx[t >> 6] = mx;
  __syncthreads();
  mx = fmaxf(fmaxf(red_mx[0], red_mx[1]), fmaxf(red_mx[2], red_mx[3]));
  float e1 = __expf(m1 - mx);
  float e2 = (t < C - 256) ? __expf(m2 - mx) : 0.f;
  float sum = e1 + e2;
  for (int m = 1; m < 64; m <<= 1) sum += __shfl_xor(sum, m, 64);
  if ((t & 63) == 0) red_sm[t >> 6] = sum;
  __syncthreads();
  sum = red_sm[0] + red_sm[1] + red_sm[2] + red_sm[3];
  batt[t] = e1 / sum;
  if (t < C - 256) batt[256 + t] = e2 / sum;
  __syncthreads();

  int dl = t & 127;
  int half = t >> 7;
  const float* cb = c + (size_t)b * C * D + d0 + dl;
  float acc = 0.f;
  for (int r = half * 192; r < half * 192 + 192; r++)
    acc += batt[r] * cb[(size_t)r * D];
  if (half == 1) part[dl] = acc;
  __syncthreads();
  if (half == 0) q2c[(size_t)b * D + d0 + dl] = acc + part[dl];
}

// ---------------- kernel 4: term4 + bias + final mask + write ---------------
__global__ __launch_bounds__(256) void k_out(
    const float* __restrict__ c, const float* __restrict__ q2c,
    const float* __restrict__ W_out, const float* __restrict__ b_out,
    const float* __restrict__ out12, const int* __restrict__ c_len,
    float* __restrict__ outp) {
  int idx = blockIdx.x;
  int b = idx / C, r = idx % C;
  const float* crow = c + (size_t)idx * D;
  const float* v = q2c + (size_t)b * D;
  int t = threadIdx.x;
  float a0 = 0.f, a1 = 0.f;
  for (int d = t * 4; d < D; d += 1024) {
    float4 cv = *(const float4*)(crow + d);
    float4 vv = *(const float4*)(v + d);
    const float* wp = W_out + (size_t)(3 * D + d) * 2;
    float4 wa = *(const float4*)(wp);
    float4 wb = *(const float4*)(wp + 4);
    float px = cv.x * vv.x, py = cv.y * vv.y;
    float pz = cv.z * vv.z, pw = cv.w * vv.w;
    a0 += px * wa.x + py * wa.z + pz * wb.x + pw * wb.z;
    a1 += px * wa.y + py * wa.w + pz * wb.y + pw * wb.w;
  }
  for (int m = 1; m < 64; m <<= 1) {
    a0 += __shfl_xor(a0, m, 64);
    a1 += __shfl_xor(a1, m, 64);
  }
  __shared__ float red[2][4];
  int w = t >> 6, lane = t & 63;
  if (lane == 0) { red[0][w] = a0; red[1][w] = a1; }
  __syncthreads();
  if (t == 0) {
    float o0 = out12[idx * 2 + 0] + red[0][0] + red[0][1] + red[0][2] +
               red[0][3] + b_out[0];
    float o1 = out12[idx * 2 + 1] + red[1][0] + red[1][1] + red[1][2] +
               red[1][3] + b_out[1];
    if (r >= c_len[b] && r < C - 1) { o0 = NEGV; o1 = NEGV; }
    outp[idx] = o0;
    outp[B * C + idx] = o1;
  }
}

extern "C" void kernel_launch(void* const* d_in, const int* in_sizes, int n_in,
                              void* d_out, int out_size, void* d_ws,
                              size_t ws_size, hipStream_t stream) {
  const float* c = (const float*)d_in[0];
  const float* q = (const float*)d_in[1];
  const int* c_len = (const int*)d_in[2];
  const int* q_len = (const int*)d_in[3];
  const float* w_c = (const float*)d_in[4];
  const float* b_c = (const float*)d_in[5];
  const float* w_q = (const float*)d_in[6];
  const float* b_q = (const float*)d_in[7];
  const float* w_cq = (const float*)d_in[8];
  const float* b_cq = (const float*)d_in[9];
  const float* W_out = (const float*)d_in[10];
  const float* b_out = (const float*)d_in[11];
  float* outp = (float*)d_out;

  float* ws = (float*)d_ws;
  float* qstats = ws;                     // B*Q*3  = 3072
  float* mrow = ws + 3072;                // B*C    = 6144
  float* out12 = ws + 3072 + 6144;        // B*C*2  = 12288
  float* q2c = ws + 3072 + 6144 + 12288;  // B*D    = 32768

  hipLaunchKernelGGL(k_qstats, dim3(B * Q), dim3(256), 0, stream, q, w_q,
                     W_out, qstats);
  hipLaunchKernelGGL(k_gemm, dim3(C / MB, B), dim3(256), 0, stream, c, q,
                     c_len, q_len, w_c, b_c, b_q, w_cq, b_cq, W_out, qstats,
                     mrow, out12);
  hipLaunchKernelGGL(k_q2c, dim3(16, B), dim3(256), 0, stream, c, mrow, q2c);
  hipLaunchKernelGGL(k_out, dim3(B * C), dim3(256), 0, stream, c, q2c, W_out,
                     b_out, out12, c_len, outp);
}

// Round 3
// 88.389 us; speedup vs baseline: 2.1300x; 1.5711x over previous
//
#include <hip/hip_runtime.h>

#define NEGV -1.0e12f
constexpr int B = 16, C = 384, Q = 64, D = 2048;
constexpr int MT = 16;       // c-rows per block in k_gemm
constexpr int NSTEP = 32;    // K steps of 64
constexpr int IMG = 16384;   // shorts per (b,step) B-image (32768 B = 8 glds/thread)
constexpr int PITCH = 72;    // shorts per B row (144 B: 16B-aligned, 2-way banks)

typedef __attribute__((ext_vector_type(8))) short s16x8;
typedef __attribute__((ext_vector_type(4))) float f32x4;
typedef __attribute__((ext_vector_type(4))) unsigned u32x4;

__device__ __forceinline__ unsigned pkbf(float lo, float hi) {
  unsigned ulo = __builtin_bit_cast(unsigned, lo);
  unsigned uhi = __builtin_bit_cast(unsigned, hi);
  return (uhi & 0xFFFF0000u) | (ulo >> 16);
}

// ---------------- kernel 0: pre-pack B matrix images into ws ----------------
// B rows per (b, kstep=64): [0,64): q*w_cq, [64,128): q*W3c0, [128,192): q*W3c1,
// 192: w_c, 193: W1c0, 194: W1c1. bf16, pitch 72 shorts, image = 16384 shorts.
__global__ __launch_bounds__(256) void k_prep(
    const float* __restrict__ q, const float* __restrict__ w_cq,
    const float* __restrict__ w_c, const float* __restrict__ W_out,
    unsigned short* __restrict__ bpk) {
  const int s = blockIdx.x, b = blockIdx.y;
  const int k0 = s * 64;
  unsigned short* img = bpk + ((size_t)b * NSTEP + s) * IMG;
  const int t = threadIdx.x;
#pragma unroll
  for (int i = 0; i < 4; ++i) {
    int idx = t + 256 * i;            // 0..1023
    int qi = idx >> 4, kc = (idx & 15) * 4;
    float4 qv = *(const float4*)(q + ((size_t)b * Q + qi) * D + k0 + kc);
    float4 wq = *(const float4*)(w_cq + k0 + kc);
    const float* wp = W_out + (size_t)(2 * D + k0 + kc) * 2;  // W3 rows
    float4 wa = *(const float4*)(wp);
    float4 wb = *(const float4*)(wp + 4);
    uint2 u;
    u.x = pkbf(qv.x * wq.x, qv.y * wq.y);
    u.y = pkbf(qv.z * wq.z, qv.w * wq.w);
    *(uint2*)(img + qi * PITCH + kc) = u;
    u.x = pkbf(qv.x * wa.x, qv.y * wa.z);
    u.y = pkbf(qv.z * wb.x, qv.w * wb.z);
    *(uint2*)(img + (64 + qi) * PITCH + kc) = u;
    u.x = pkbf(qv.x * wa.y, qv.y * wa.w);
    u.y = pkbf(qv.z * wb.y, qv.w * wb.w);
    *(uint2*)(img + (128 + qi) * PITCH + kc) = u;
  }
  if (t < 48) {  // stats rows 192..194
    int r = t >> 4, kc = (t & 15) * 4;
    uint2 u;
    if (r == 0) {
      float4 w = *(const float4*)(w_c + k0 + kc);
      u.x = pkbf(w.x, w.y);
      u.y = pkbf(w.z, w.w);
    } else {
      const float* wp = W_out + (size_t)(k0 + kc) * 2 + (r - 1);  // W1 col r-1
      u.x = pkbf(wp[0], wp[2]);
      u.y = pkbf(wp[4], wp[6]);
    }
    *(uint2*)(img + (192 + r) * PITCH + kc) = u;
  }
}

// ---------------- kernel 1: per (b,i) q stats: q.w_q, q.W2col0, q.W2col1 ----
__global__ __launch_bounds__(256) void k_qstats(
    const float* __restrict__ q, const float* __restrict__ w_q,
    const float* __restrict__ W_out, float* __restrict__ qstats) {
  int bi = blockIdx.x;
  const float* qrow = q + (size_t)bi * D;
  int t = threadIdx.x;
  float a0 = 0.f, a1 = 0.f, a2 = 0.f;
  for (int d = t * 4; d < D; d += 256 * 4) {
    float4 qv = *(const float4*)(qrow + d);
    float4 wq = *(const float4*)(w_q + d);
    const float* wp = W_out + (size_t)(D + d) * 2;
    float4 wa = *(const float4*)(wp);
    float4 wb = *(const float4*)(wp + 4);
    a0 += qv.x * wq.x + qv.y * wq.y + qv.z * wq.z + qv.w * wq.w;
    a1 += qv.x * wa.x + qv.y * wa.z + qv.z * wb.x + qv.w * wb.z;
    a2 += qv.x * wa.y + qv.y * wa.w + qv.z * wb.y + qv.w * wb.w;
  }
  for (int m = 1; m < 64; m <<= 1) {
    a0 += __shfl_xor(a0, m, 64);
    a1 += __shfl_xor(a1, m, 64);
    a2 += __shfl_xor(a2, m, 64);
  }
  __shared__ float red[3][4];
  int w = t >> 6, lane = t & 63;
  if (lane == 0) { red[0][w] = a0; red[1][w] = a1; red[2][w] = a2; }
  __syncthreads();
  if (t == 0) {
    qstats[bi * 3 + 0] = red[0][0] + red[0][1] + red[0][2] + red[0][3];
    qstats[bi * 3 + 1] = red[1][0] + red[1][1] + red[1][2] + red[1][3];
    qstats[bi * 3 + 2] = red[2][0] + red[2][1] + red[2][2] + red[2][3];
  }
}

// ---------------- kernel 2: MFMA GEMM (glds-staged B, reg A) + softmax ------
// grid (C/MT, B), 256 threads. N=208: 13 frags -> waves get 4,3,3,3.
__global__ __launch_bounds__(256, 2) void k_gemm(
    const unsigned short* __restrict__ bpk, const float* __restrict__ c,
    const int* __restrict__ c_len, const int* __restrict__ q_len,
    const float* __restrict__ b_c, const float* __restrict__ b_q,
    const float* __restrict__ b_cq, const float* __restrict__ qstats,
    float* __restrict__ mrow, float* __restrict__ out12) {
  const int t = threadIdx.x;
  const int lane = t & 63, wv = t >> 6;
  const int b = blockIdx.y, r0 = blockIdx.x * MT;
  const int lr = lane & 15, lg = lane >> 4;

  __shared__ union SM {
    unsigned short bb[2][IMG];
    float S3[MT][212];
  } sm;

  const float* pA = c + ((size_t)b * C + r0 + lr) * D + lg * 8;
  const unsigned short* gbase = bpk + (size_t)b * NSTEP * IMG + t * 8;

  const int f0 = (wv == 0) ? 0 : (1 + 3 * wv);
  const int nf = (wv == 0) ? 4 : 3;

  f32x4 acc[4];
#pragma unroll
  for (int f = 0; f < 4; ++f) acc[f] = f32x4{0.f, 0.f, 0.f, 0.f};

  float4 rAe[4], rAo[4];

  auto stage = [&](int buf, int s) {
    const unsigned short* g = gbase + (size_t)s * IMG;
#pragma unroll
    for (int i = 0; i < 8; ++i)
      __builtin_amdgcn_global_load_lds(
          (const __attribute__((address_space(1))) unsigned*)(g + i * 2048),
          (__attribute__((address_space(3))) unsigned*)(
              &sm.bb[buf][i * 2048 + wv * 512]),
          16, 0, 0);
  };
  auto loadA = [&](float4* r, int s) {
    const float* p = pA + s * 64;
    r[0] = *(const float4*)(p);
    r[1] = *(const float4*)(p + 4);
    r[2] = *(const float4*)(p + 32);
    r[3] = *(const float4*)(p + 36);
  };
  auto compute = [&](const float4* r, const unsigned short* bbuf) {
#pragma unroll
    for (int h = 0; h < 2; ++h) {
      float4 lo = r[2 * h], hi = r[2 * h + 1];
      u32x4 au = {pkbf(lo.x, lo.y), pkbf(lo.z, lo.w), pkbf(hi.x, hi.y),
                  pkbf(hi.z, hi.w)};
      s16x8 af = __builtin_bit_cast(s16x8, au);
#pragma unroll
      for (int f = 0; f < 4; ++f)
        if (f < nf) {
          s16x8 bf = *(const s16x8*)(bbuf + ((f0 + f) * 16 + lr) * PITCH +
                                     h * 32 + lg * 8);
          acc[f] =
              __builtin_amdgcn_mfma_f32_16x16x32_bf16(af, bf, acc[f], 0, 0, 0);
        }
    }
  };

  stage(0, 0);
  loadA(rAe, 0);
  for (int s2 = 0; s2 < 16; ++s2) {
    __syncthreads();                       // buf1 free (readers of s-1 done)
    stage(1, 2 * s2 + 1);
    loadA(rAo, 2 * s2 + 1);
    asm volatile("s_waitcnt vmcnt(12)" ::: "memory");  // batch(2*s2) landed
    __syncthreads();                       // publish buf0 across waves
    compute(rAe, sm.bb[0]);
    __syncthreads();                       // buf0 free
    if (s2 < 15) {
      stage(0, 2 * s2 + 2);
      loadA(rAe, 2 * s2 + 2);
      asm volatile("s_waitcnt vmcnt(12)" ::: "memory");
    } else {
      asm volatile("s_waitcnt vmcnt(0)" ::: "memory");
    }
    __syncthreads();                       // publish buf1
    compute(rAo, sm.bb[1]);
  }

  // ---- epilogue: frags -> S3, then per-row softmax/reduce ----
  __syncthreads();
#pragma unroll
  for (int f = 0; f < 4; ++f)
    if (f < nf) {
      int colb = (f0 + f) * 16 + lr;
      int rb = lg * 4;
#pragma unroll
      for (int r2 = 0; r2 < 4; ++r2) sm.S3[rb + r2][colb] = acc[f][r2];
    }
  __syncthreads();

  const int cl = c_len[b], ql = q_len[b];
  const float bias = b_c[0] + b_q[0] + b_cq[0];
  const float qs0 = qstats[((b << 6) + lane) * 3 + 0];
  const float qs1 = qstats[((b << 6) + lane) * 3 + 1];
  const float qs2 = qstats[((b << 6) + lane) * 3 + 2];
#pragma unroll
  for (int rr = 0; rr < 4; ++rr) {
    int row = wv * 4 + rr;
    int rg = r0 + row;
    float s = sm.S3[row][lane] + sm.S3[row][192] + qs0 + bias;
    bool masked = (lane >= ql) || ((rg >= cl) && (lane < Q - 1));
    if (masked) s += NEGV;
    float mx = s;
    for (int m = 1; m < 64; m <<= 1) mx = fmaxf(mx, __shfl_xor(mx, m, 64));
    float e = __expf(s - mx);
    float den = e;
    for (int m = 1; m < 64; m <<= 1) den += __shfl_xor(den, m, 64);
    float a = e / den;
    float v0 = a * qs1;
    float v1 = a * qs2;
    float v2 = a * sm.S3[row][64 + lane];
    float v3 = a * sm.S3[row][128 + lane];
    for (int m = 1; m < 64; m <<= 1) {
      v0 += __shfl_xor(v0, m, 64);
      v1 += __shfl_xor(v1, m, 64);
      v2 += __shfl_xor(v2, m, 64);
      v3 += __shfl_xor(v3, m, 64);
    }
    if (lane == 0) {
      mrow[b * C + rg] = mx;
      out12[(b * C + rg) * 2 + 0] = sm.S3[row][193] + v0 + v2;
      out12[(b * C + rg) * 2 + 1] = sm.S3[row][194] + v1 + v3;
    }
  }
}

// ---------------- kernel 3: b_att softmax + q2c ------------------------------
__global__ __launch_bounds__(256) void k_q2c(const float* __restrict__ c,
                                             const float* __restrict__ mrow,
                                             float* __restrict__ q2c) {
  int b = blockIdx.y;
  int d0 = blockIdx.x * 128;
  int t = threadIdx.x;
  __shared__ float batt[C];
  __shared__ float red_mx[4];
  __shared__ float red_sm[4];
  __shared__ float part[128];

  float m1 = mrow[b * C + t];
  float m2 = (t < C - 256) ? mrow[b * C + 256 + t] : -3.0e38f;
  float mx = fmaxf(m1, m2);
  for (int m = 1; m < 64; m <<= 1) mx = fmaxf(mx, __shfl_xor(mx, m, 64));
  if ((t & 63) == 0) red_mx[t >> 6] = mx;
  __syncthreads();
  mx = fmaxf(fmaxf(red_mx[0], red_mx[1]), fmaxf(red_mx[2], red_mx[3]));
  float e1 = __expf(m1 - mx);
  float e2 = (t < C - 256) ? __expf(m2 - mx) : 0.f;
  float sum = e1 + e2;
  for (int m = 1; m < 64; m <<= 1) sum += __shfl_xor(sum, m, 64);
  if ((t & 63) == 0) red_sm[t >> 6] = sum;
  __syncthreads();
  sum = red_sm[0] + red_sm[1] + red_sm[2] + red_sm[3];
  batt[t] = e1 / sum;
  if (t < C - 256) batt[256 + t] = e2 / sum;
  __syncthreads();

  int dl = t & 127;
  int half = t >> 7;
  const float* cb = c + (size_t)b * C * D + d0 + dl;
  float acc = 0.f;
  for (int r = half * 192; r < half * 192 + 192; r++)
    acc += batt[r] * cb[(size_t)r * D];
  if (half == 1) part[dl] = acc;
  __syncthreads();
  if (half == 0) q2c[(size_t)b * D + d0 + dl] = acc + part[dl];
}

// ---------------- kernel 4: term4 + bias + final mask + write ---------------
__global__ __launch_bounds__(256) void k_out(
    const float* __restrict__ c, const float* __restrict__ q2c,
    const float* __restrict__ W_out, const float* __restrict__ b_out,
    const float* __restrict__ out12, const int* __restrict__ c_len,
    float* __restrict__ outp) {
  int idx = blockIdx.x;
  int b = idx / C, r = idx % C;
  const float* crow = c + (size_t)idx * D;
  const float* v = q2c + (size_t)b * D;
  int t = threadIdx.x;
  float a0 = 0.f, a1 = 0.f;
  for (int d = t * 4; d < D; d += 1024) {
    float4 cv = *(const float4*)(crow + d);
    float4 vv = *(const float4*)(v + d);
    const float* wp = W_out + (size_t)(3 * D + d) * 2;
    float4 wa = *(const float4*)(wp);
    float4 wb = *(const float4*)(wp + 4);
    float px = cv.x * vv.x, py = cv.y * vv.y;
    float pz = cv.z * vv.z, pw = cv.w * vv.w;
    a0 += px * wa.x + py * wa.z + pz * wb.x + pw * wb.z;
    a1 += px * wa.y + py * wa.w + pz * wb.y + pw * wb.w;
  }
  for (int m = 1; m < 64; m <<= 1) {
    a0 += __shfl_xor(a0, m, 64);
    a1 += __shfl_xor(a1, m, 64);
  }
  __shared__ float red[2][4];
  int w = t >> 6, lane = t & 63;
  if (lane == 0) { red[0][w] = a0; red[1][w] = a1; }
  __syncthreads();
  if (t == 0) {
    float o0 = out12[idx * 2 + 0] + red[0][0] + red[0][1] + red[0][2] +
               red[0][3] + b_out[0];
    float o1 = out12[idx * 2 + 1] + red[1][0] + red[1][1] + red[1][2] +
               red[1][3] + b_out[1];
    if (r >= c_len[b] && r < C - 1) { o0 = NEGV; o1 = NEGV; }
    outp[idx] = o0;
    outp[B * C + idx] = o1;
  }
}

extern "C" void kernel_launch(void* const* d_in, const int* in_sizes, int n_in,
                              void* d_out, int out_size, void* d_ws,
                              size_t ws_size, hipStream_t stream) {
  const float* c = (const float*)d_in[0];
  const float* q = (const float*)d_in[1];
  const int* c_len = (const int*)d_in[2];
  const int* q_len = (const int*)d_in[3];
  const float* w_c = (const float*)d_in[4];
  const float* b_c = (const float*)d_in[5];
  const float* w_q = (const float*)d_in[6];
  const float* b_q = (const float*)d_in[7];
  const float* w_cq = (const float*)d_in[8];
  const float* b_cq = (const float*)d_in[9];
  const float* W_out = (const float*)d_in[10];
  const float* b_out = (const float*)d_in[11];
  float* outp = (float*)d_out;

  // ws layout: B_pack images (16.78 MB) then small f32 buffers
  unsigned short* bpk = (unsigned short*)d_ws;
  float* ws = (float*)d_ws + (size_t)B * NSTEP * IMG / 2;  // float offset 4194304
  float* qstats = ws;                     // B*Q*3  = 3072
  float* mrow = ws + 3072;                // B*C    = 6144
  float* out12 = ws + 3072 + 6144;        // B*C*2  = 12288
  float* q2c = ws + 3072 + 6144 + 12288;  // B*D    = 32768

  hipLaunchKernelGGL(k_prep, dim3(NSTEP, B), dim3(256), 0, stream, q, w_cq,
                     w_c, W_out, bpk);
  hipLaunchKernelGGL(k_qstats, dim3(B * Q), dim3(256), 0, stream, q, w_q,
                     W_out, qstats);
  hipLaunchKernelGGL(k_gemm, dim3(C / MT, B), dim3(256), 0, stream, bpk, c,
                     c_len, q_len, b_c, b_q, b_cq, qstats, mrow, out12);
  hipLaunchKernelGGL(k_q2c, dim3(16, B), dim3(256), 0, stream, c, mrow, q2c);
  hipLaunchKernelGGL(k_out, dim3(B * C), dim3(256), 0, stream, c, q2c, W_out,
                     b_out, out12, c_len, outp);
}